// Round 1
// baseline (3407.552 us; speedup 1.0000x reference)
//
#include <hip/hip_runtime.h>
#include <hip/hip_bf16.h>
#include <math.h>

// ChannelMambaBlock fused kernel — Round 1 (correctness-first f32-VALU baseline)
// B=4, C=192, H=128, W=128, K=4, DSTATE=8, DTRANK=12
// One workgroup = 32 consecutive-W pixels; whole chain fused; activations bf16 in LDS,
// weights f32 streamed from global (L2-resident); f32 accumulation everywhere.

#define CC    192
#define HH    128
#define WW    128
#define BB    4
#define NK    4
#define DST   8
#define DTR   12
#define TP    32          // pixels per tile
#define SP    196         // LDS row stride in bf16 elems (padded, 8B-aligned rows)
#define NTH   256

__device__ __forceinline__ float bf2f(unsigned short u) {
    union { unsigned int i; float f; } v; v.i = ((unsigned int)u) << 16; return v.f;
}
__device__ __forceinline__ unsigned short f2bf(float f) {
    union { float f; unsigned int i; } v; v.f = f;
    unsigned int r = (v.i + 0x7fffu + ((v.i >> 16) & 1u)) >> 16;  // RNE
    return (unsigned short)r;
}
__device__ __forceinline__ float siluf(float x) { return x / (1.f + expf(-x)); }
__device__ __forceinline__ float softplusf(float x) {
    return fmaxf(x, 0.f) + log1pf(expf(-fabsf(x)));
}

// Register-tiled GEMM: thread computes 2 pixels x 4 outputs; K-loop over KD.
// sIn: [TP][SP] bf16 activations (row-major, K contiguous). W: row-major [N][KD] f32.
template<int KD>
__device__ __forceinline__ void gemm_block(const unsigned short* sIn,
                                           const float* __restrict__ W,
                                           int px0, int o0, float acc[2][4])
{
    const float* w0 = W + (size_t)o0 * KD;
    const unsigned short* a0p = sIn + px0 * SP;
    const unsigned short* a1p = a0p + SP;
#pragma unroll 2
    for (int d = 0; d < KD; d += 4) {
        ushort4 ua = *(const ushort4*)(a0p + d);
        ushort4 ub = *(const ushort4*)(a1p + d);
        float4 w0v = *(const float4*)(w0 + d);
        float4 w1v = *(const float4*)(w0 + KD + d);
        float4 w2v = *(const float4*)(w0 + 2 * KD + d);
        float4 w3v = *(const float4*)(w0 + 3 * KD + d);
        float a0 = bf2f(ua.x), a1 = bf2f(ua.y), a2 = bf2f(ua.z), a3 = bf2f(ua.w);
        float b0 = bf2f(ub.x), b1 = bf2f(ub.y), b2 = bf2f(ub.z), b3 = bf2f(ub.w);
        acc[0][0] += a0*w0v.x + a1*w0v.y + a2*w0v.z + a3*w0v.w;
        acc[0][1] += a0*w1v.x + a1*w1v.y + a2*w1v.z + a3*w1v.w;
        acc[0][2] += a0*w2v.x + a1*w2v.y + a2*w2v.z + a3*w2v.w;
        acc[0][3] += a0*w3v.x + a1*w3v.y + a2*w3v.z + a3*w3v.w;
        acc[1][0] += b0*w0v.x + b1*w0v.y + b2*w0v.z + b3*w0v.w;
        acc[1][1] += b0*w1v.x + b1*w1v.y + b2*w1v.z + b3*w1v.w;
        acc[1][2] += b0*w2v.x + b1*w2v.y + b2*w2v.z + b3*w2v.w;
        acc[1][3] += b0*w3v.x + b1*w3v.y + b2*w3v.z + b3*w3v.w;
    }
}

extern "C" __global__ void __launch_bounds__(NTH, 3)
mamba_fused(const float* __restrict__ x,
            const float* __restrict__ norm_w,  const float* __restrict__ norm_b,
            const float* __restrict__ w_in,    const float* __restrict__ ssm_in_w,
            const float* __restrict__ x_proj_w,const float* __restrict__ dt_w,
            const float* __restrict__ dt_b,    const float* __restrict__ Ds,
            const float* __restrict__ out_norm_w, const float* __restrict__ out_norm_b,
            const float* __restrict__ ssm_out_w,  const float* __restrict__ w_out,
            float* __restrict__ out)
{
    __shared__ __align__(16) unsigned short sA [TP][SP];
    __shared__ __align__(16) unsigned short sB [TP][SP];
    __shared__ __align__(16) unsigned short sZ [TP][SP];
    __shared__ __align__(16) unsigned short sX2[TP][SP];
    __shared__ float sred [TP][8];
    __shared__ float sred2[TP][8];
    __shared__ float smu[TP];
    __shared__ float srs[TP];
    __shared__ float sbc[TP][NK];

    const int tid = threadIdx.x;
    const int t   = blockIdx.x;            // 2048 tiles
    const int b   = t >> 9;                // 512 tiles per batch (128 h * 4 w-tiles)
    const int rem = t & 511;
    const int h   = rem >> 2;
    const int w0g = (rem & 3) * TP;

    // ---------------- Phase 0: load x + LayerNorm1 -> sA = xn (bf16) -------------
    {
        const int px = tid & 31, part = tid >> 5;   // 8 parts x 24 channels
        float sum = 0.f, sq = 0.f;
        const size_t base = (((size_t)b * CC) * HH + h) * WW + w0g + px;
        for (int i = 0; i < 24; ++i) {
            int c = part * 24 + i;
            float v = x[base + (size_t)c * (HH * WW)];
            sum += v; sq += v * v;
            sA[px][c] = f2bf(v);
        }
        sred[px][part] = sum; sred2[px][part] = sq;
        __syncthreads();
        if (part == 0) {
            float s = 0.f, q = 0.f;
            for (int j = 0; j < 8; ++j) { s += sred[px][j]; q += sred2[px][j]; }
            float mu  = s * (1.f / CC);
            float var = q * (1.f / CC) - mu * mu;
            smu[px] = mu; srs[px] = rsqrtf(var + 1e-5f);
        }
        __syncthreads();
        const float mu = smu[px], rs = srs[px];
        for (int i = 0; i < 24; ++i) {
            int c = part * 24 + i;
            float v = bf2f(sA[px][c]);
            v = (v - mu) * rs * norm_w[c] + norm_b[c];
            sA[px][c] = f2bf(v);
        }
        __syncthreads();
    }

    const int og  = tid & 15;
    const int pg  = tid >> 4;
    const int px0 = pg * 2;

    // ---------------- GEMM1: p = xn @ w_in^T (N=384) -> sB=x1, sX2=silu(x2) ------
#pragma unroll 1
    for (int pass = 0; pass < 6; ++pass) {
        int o0 = pass * 64 + og * 4;
        float acc[2][4] = {{0,0,0,0},{0,0,0,0}};
        gemm_block<CC>(&sA[0][0], w_in, px0, o0, acc);
#pragma unroll
        for (int j = 0; j < 2; ++j)
#pragma unroll
            for (int i = 0; i < 4; ++i) {
                int o = o0 + i;
                if (o < CC) sB [px0+j][o]      = f2bf(acc[j][i]);
                else        sX2[px0+j][o - CC] = f2bf(siluf(acc[j][i]));
            }
    }
    __syncthreads();

    // ---------------- GEMM2: u = x1 @ ssm_in_w^T -> sA=silu(xss), sZ=silu(z) -----
#pragma unroll 1
    for (int pass = 0; pass < 6; ++pass) {
        int o0 = pass * 64 + og * 4;
        float acc[2][4] = {{0,0,0,0},{0,0,0,0}};
        gemm_block<CC>(&sB[0][0], ssm_in_w, px0, o0, acc);
#pragma unroll
        for (int j = 0; j < 2; ++j)
#pragma unroll
            for (int i = 0; i < 4; ++i) {
                int o = o0 + i;
                float v = siluf(acc[j][i]);
                if (o < CC) sA[px0+j][o]      = f2bf(v);
                else        sZ[px0+j][o - CC] = f2bf(v);
            }
    }
    __syncthreads();

    // ---------------- GEMM3: xd = xss @ x_proj^T (N=112) -> sB ------------------
#pragma unroll 1
    for (int pass = 0; pass < 2; ++pass) {
        int o0 = pass * 64 + og * 4;
        if (o0 < NK * 28) {
            float acc[2][4] = {{0,0,0,0},{0,0,0,0}};
            gemm_block<CC>(&sA[0][0], x_proj_w, px0, o0, acc);
#pragma unroll
            for (int j = 0; j < 2; ++j)
#pragma unroll
                for (int i = 0; i < 4; ++i) {
                    int o = o0 + i;
                    if (o < NK * 28) sB[px0+j][o] = f2bf(acc[j][i]);
                }
        }
    }
    __syncthreads();

    // ---------------- bc[px][k] = dot(Bv, Cv) -----------------------------------
    if (tid < TP * NK) {
        int px = tid & 31, k = tid >> 5;
        float a = 0.f;
        for (int s = 0; s < DST; ++s)
            a += bf2f(sB[px][k*28 + DTR + s]) * bf2f(sB[px][k*28 + DTR + DST + s]);
        sbc[px][k] = a;
    }
    __syncthreads();

    // ---------------- dt/gain + y = xss*gain, LN2, *z -> sA ---------------------
    {
        const int px = tid & 31, part = tid >> 5;
        float dtf[NK][DTR];
#pragma unroll
        for (int k = 0; k < NK; ++k)
#pragma unroll
            for (int r = 0; r < DTR; ++r)
                dtf[k][r] = bf2f(sB[px][k*28 + r]);
        float bck[NK] = { sbc[px][0], sbc[px][1], sbc[px][2], sbc[px][3] };

        float sum = 0.f, sq = 0.f;
        for (int i = 0; i < 24; ++i) {
            int c = part * 24 + i;
            float g = 0.f;
#pragma unroll
            for (int k = 0; k < NK; ++k) {
                const float* dw = dt_w + ((size_t)(k * CC + c)) * DTR;
                float4 d0 = *(const float4*)(dw);
                float4 d1 = *(const float4*)(dw + 4);
                float4 d2 = *(const float4*)(dw + 8);
                float dot = dt_b[k * CC + c];
                dot += dtf[k][0]*d0.x + dtf[k][1]*d0.y + dtf[k][2]*d0.z + dtf[k][3]*d0.w;
                dot += dtf[k][4]*d1.x + dtf[k][5]*d1.y + dtf[k][6]*d1.z + dtf[k][7]*d1.w;
                dot += dtf[k][8]*d2.x + dtf[k][9]*d2.y + dtf[k][10]*d2.z + dtf[k][11]*d2.w;
                g += bck[k] * softplusf(dot) + Ds[k * CC + c];
            }
            float yv = bf2f(sA[px][c]) * g;
            sum += yv; sq += yv * yv;
            sA[px][c] = f2bf(yv);
        }
        sred[px][part] = sum; sred2[px][part] = sq;
        __syncthreads();
        if (part == 0) {
            float s = 0.f, q = 0.f;
            for (int j = 0; j < 8; ++j) { s += sred[px][j]; q += sred2[px][j]; }
            float mu  = s * (1.f / CC);
            float var = q * (1.f / CC) - mu * mu;
            smu[px] = mu; srs[px] = rsqrtf(var + 1e-5f);
        }
        __syncthreads();
        const float mu = smu[px], rs = srs[px];
        for (int i = 0; i < 24; ++i) {
            int c = part * 24 + i;
            float v = bf2f(sA[px][c]);
            v = (v - mu) * rs * out_norm_w[c] + out_norm_b[c];
            v *= bf2f(sZ[px][c]);                 // *silu(z)
            sA[px][c] = f2bf(v);
        }
        __syncthreads();
    }

    // ---------------- GEMM4: s = yz @ ssm_out^T; sB = s * silu(x2) --------------
#pragma unroll 1
    for (int pass = 0; pass < 3; ++pass) {
        int o0 = pass * 64 + og * 4;
        float acc[2][4] = {{0,0,0,0},{0,0,0,0}};
        gemm_block<CC>(&sA[0][0], ssm_out_w, px0, o0, acc);
#pragma unroll
        for (int j = 0; j < 2; ++j)
#pragma unroll
            for (int i = 0; i < 4; ++i) {
                int o = o0 + i;
                sB[px0+j][o] = f2bf(acc[j][i] * bf2f(sX2[px0+j][o]));
            }
    }
    __syncthreads();

    // ---------------- GEMM5: o = sB @ w_out^T; out = x + o ----------------------
#pragma unroll 1
    for (int pass = 0; pass < 3; ++pass) {
        int o0 = pass * 64 + og * 4;
        float acc[2][4] = {{0,0,0,0},{0,0,0,0}};
        gemm_block<CC>(&sB[0][0], w_out, px0, o0, acc);
#pragma unroll
        for (int i = 0; i < 4; ++i) {
            int o = o0 + i;
            size_t g = (((size_t)b * CC + o) * HH + h) * WW + w0g + px0;
            out[g]     = x[g]     + acc[0][i];
            out[g + 1] = x[g + 1] + acc[1][i];
        }
    }
}

extern "C" void kernel_launch(void* const* d_in, const int* in_sizes, int n_in,
                              void* d_out, int out_size, void* d_ws, size_t ws_size,
                              hipStream_t stream) {
    const float* x          = (const float*)d_in[0];
    const float* norm_w     = (const float*)d_in[1];
    const float* norm_b     = (const float*)d_in[2];
    const float* w_in       = (const float*)d_in[3];
    const float* ssm_in_w   = (const float*)d_in[4];
    const float* x_proj_w   = (const float*)d_in[5];
    const float* dt_w       = (const float*)d_in[6];
    const float* dt_b       = (const float*)d_in[7];
    // d_in[8] = A_logs : unused by the reference computation
    const float* Ds         = (const float*)d_in[9];
    const float* out_norm_w = (const float*)d_in[10];
    const float* out_norm_b = (const float*)d_in[11];
    const float* ssm_out_w  = (const float*)d_in[12];
    const float* w_out      = (const float*)d_in[13];

    dim3 grid(2048), block(NTH);
    mamba_fused<<<grid, block, 0, stream>>>(x, norm_w, norm_b, w_in, ssm_in_w,
                                            x_proj_w, dt_w, dt_b, Ds,
                                            out_norm_w, out_norm_b,
                                            ssm_out_w, w_out, (float*)d_out);
}

// Round 2
// 302.128 us; speedup vs baseline: 11.2785x; 11.2785x over previous
//
#include <hip/hip_runtime.h>
#include <hip/hip_bf16.h>
#include <math.h>

// ChannelMambaBlock fused kernel — Round 2: MFMA bf16 GEMMs
// B=4, C=192, H=128, W=128, K=4, DSTATE=8, DTRANK=12
// One WG = 32 consecutive-W pixels; 256 threads = 4 waves.
// GEMMs use v_mfma_f32_16x16x32_bf16: A (activations) from LDS, B (weights,
// pre-converted to bf16 in d_ws by prep_w) from global (L2-resident).

#define CC    192
#define HH    128
#define WW    128
#define NK    4
#define DST   8
#define DTR   12
#define TP    32
#define SP    200         // LDS row stride (bf16 elems): 400B rows, 16B-aligned
#define NTH   256

typedef __attribute__((ext_vector_type(8))) short bh8;   // 8 bf16 = 4 VGPR
typedef __attribute__((ext_vector_type(4))) float f4;

// bf16 weight segment offsets inside d_ws (ushort elems)
#define OFF_WIN    0
#define OFF_SSMIN  73728        // 384*192
#define OFF_XPROJ  147456       // + 384*192
#define OFF_SSMOUT 168960       // + 112*192
#define OFF_WOUT   205824       // + 192*192
#define WTOT       242688       // + 192*192

__device__ __forceinline__ float bf2f(unsigned short u) {
    union { unsigned int i; float f; } v; v.i = ((unsigned int)u) << 16; return v.f;
}
__device__ __forceinline__ unsigned short f2bf(float f) {
    union { float f; unsigned int i; } v; v.f = f;
    unsigned int r = (v.i + 0x7fffu + ((v.i >> 16) & 1u)) >> 16;  // RNE
    return (unsigned short)r;
}
__device__ __forceinline__ float siluf(float x) { return x / (1.f + expf(-x)); }
__device__ __forceinline__ float softplusf(float x) {
    return fmaxf(x, 0.f) + log1pf(expf(-fabsf(x)));
}

extern "C" __global__ void prep_w(const float* __restrict__ w_in,
                                  const float* __restrict__ ssm_in_w,
                                  const float* __restrict__ x_proj_w,
                                  const float* __restrict__ ssm_out_w,
                                  const float* __restrict__ w_out,
                                  unsigned short* __restrict__ wb)
{
    int i = blockIdx.x * NTH + threadIdx.x;
    if (i >= WTOT) return;
    float v;
    if      (i < OFF_XPROJ ) v = (i < OFF_SSMIN) ? w_in[i] : ssm_in_w[i - OFF_SSMIN];
    else if (i < OFF_SSMOUT) v = x_proj_w[i - OFF_XPROJ];
    else if (i < OFF_WOUT  ) v = ssm_out_w[i - OFF_SSMOUT];
    else                     v = w_out[i - OFF_WOUT];
    wb[i] = f2bf(v);
}

extern "C" __global__ void __launch_bounds__(NTH, 3)
mamba_fused(const float* __restrict__ x,
            const float* __restrict__ norm_w,  const float* __restrict__ norm_b,
            const float* __restrict__ dt_w,    const float* __restrict__ dt_b,
            const float* __restrict__ Ds,
            const float* __restrict__ out_norm_w, const float* __restrict__ out_norm_b,
            const unsigned short* __restrict__ wsb,
            float* __restrict__ out)
{
    __shared__ __align__(16) unsigned short sA [TP][SP];
    __shared__ __align__(16) unsigned short sB [TP][SP];
    __shared__ __align__(16) unsigned short sZ [TP][SP];
    __shared__ __align__(16) unsigned short sX2[TP][SP];
    __shared__ float sred [TP][8];
    __shared__ float sred2[TP][8];
    __shared__ float smu[TP];
    __shared__ float srs[TP];
    __shared__ float sbc[TP][NK];

    const int tid  = threadIdx.x;
    const int lane = tid & 63;
    const int wave = tid >> 6;
    const int frow = lane & 15;     // A row-offset / B col-offset / D col-offset
    const int kb   = lane >> 4;     // 0..3 (k-block of 8; D row-block of 4)

    const int t   = blockIdx.x;
    const int b   = t >> 9;
    const int rem = t & 511;
    const int h   = rem >> 2;
    const int w0g = (rem & 3) * TP;

    // ---------------- Phase 0: load x + LayerNorm1 -> sA = xn (bf16) -------------
    {
        const int px = tid & 31, part = tid >> 5;
        float sum = 0.f, sq = 0.f;
        const size_t base = (((size_t)b * CC) * HH + h) * WW + w0g + px;
        for (int i = 0; i < 24; ++i) {
            int c = part * 24 + i;
            float v = x[base + (size_t)c * (HH * WW)];
            sum += v; sq += v * v;
            sA[px][c] = f2bf(v);
        }
        sred[px][part] = sum; sred2[px][part] = sq;
        __syncthreads();
        if (part == 0) {
            float s = 0.f, q = 0.f;
            for (int j = 0; j < 8; ++j) { s += sred[px][j]; q += sred2[px][j]; }
            float mu  = s * (1.f / CC);
            float var = q * (1.f / CC) - mu * mu;
            smu[px] = mu; srs[px] = rsqrtf(var + 1e-5f);
        }
        __syncthreads();
        const float mu = smu[px], rs = srs[px];
        for (int i = 0; i < 24; ++i) {
            int c = part * 24 + i;
            float v = bf2f(sA[px][c]);
            v = (v - mu) * rs * norm_w[c] + norm_b[c];
            sA[px][c] = f2bf(v);
        }
        __syncthreads();
    }

    // A-frag loader: lane holds A[m0 + frow][ks*32 + kb*8 .. +8] for m0 in {0,16}
    auto load_a = [&](const unsigned short* sSrc, bh8 a[2][6]) {
#pragma unroll
        for (int m = 0; m < 2; ++m)
#pragma unroll
            for (int ks = 0; ks < 6; ++ks)
                a[m][ks] = *(const bh8*)(sSrc + (m * 16 + frow) * SP + ks * 32 + kb * 8);
    };
    // One 32x16 output tile (both m-halves) vs weight rows [n0..n0+16) x [0..192)
    auto gemm_nt = [&](const bh8 a[2][6], const unsigned short* wB, int n0,
                       f4& acc0, f4& acc1) {
        const unsigned short* wp = wB + (size_t)(n0 + frow) * CC + kb * 8;
#pragma unroll
        for (int ks = 0; ks < 6; ++ks) {
            bh8 bf = *(const bh8*)(wp + ks * 32);
            acc0 = __builtin_amdgcn_mfma_f32_16x16x32_bf16(a[0][ks], bf, acc0, 0, 0, 0);
            acc1 = __builtin_amdgcn_mfma_f32_16x16x32_bf16(a[1][ks], bf, acc1, 0, 0, 0);
        }
    };
    const int pxb = kb * 4;   // D rows pxb..pxb+3 (m0=0) and 16+pxb.. (m0=16)

    // ---------------- GEMM1: p = xn @ w_in^T (N=384) -> sB=x1, sX2=silu(x2) ------
    {
        bh8 a[2][6]; load_a(&sA[0][0], a);
        const unsigned short* wB = wsb + OFF_WIN;
        for (int nt = wave; nt < 24; nt += 4) {
            f4 acc0 = {0.f,0.f,0.f,0.f}, acc1 = {0.f,0.f,0.f,0.f};
            gemm_nt(a, wB, nt * 16, acc0, acc1);
            int o = nt * 16 + frow;
            if (o < CC) {
#pragma unroll
                for (int r = 0; r < 4; ++r) {
                    sB[pxb + r][o]      = f2bf(acc0[r]);
                    sB[16 + pxb + r][o] = f2bf(acc1[r]);
                }
            } else {
                int oc = o - CC;
#pragma unroll
                for (int r = 0; r < 4; ++r) {
                    sX2[pxb + r][oc]      = f2bf(siluf(acc0[r]));
                    sX2[16 + pxb + r][oc] = f2bf(siluf(acc1[r]));
                }
            }
        }
    }
    __syncthreads();

    // ---------------- GEMM2: u = x1 @ ssm_in^T -> sA=silu(xss), sZ=silu(z) -------
    {
        bh8 a[2][6]; load_a(&sB[0][0], a);
        const unsigned short* wB = wsb + OFF_SSMIN;
        for (int nt = wave; nt < 24; nt += 4) {
            f4 acc0 = {0.f,0.f,0.f,0.f}, acc1 = {0.f,0.f,0.f,0.f};
            gemm_nt(a, wB, nt * 16, acc0, acc1);
            int o = nt * 16 + frow;
            if (o < CC) {
#pragma unroll
                for (int r = 0; r < 4; ++r) {
                    sA[pxb + r][o]      = f2bf(siluf(acc0[r]));
                    sA[16 + pxb + r][o] = f2bf(siluf(acc1[r]));
                }
            } else {
                int oc = o - CC;
#pragma unroll
                for (int r = 0; r < 4; ++r) {
                    sZ[pxb + r][oc]      = f2bf(siluf(acc0[r]));
                    sZ[16 + pxb + r][oc] = f2bf(siluf(acc1[r]));
                }
            }
        }
    }
    __syncthreads();

    // ---------------- GEMM3: xd = xss @ x_proj^T (N=112) -> sB ------------------
    {
        bh8 a[2][6]; load_a(&sA[0][0], a);
        const unsigned short* wB = wsb + OFF_XPROJ;
        for (int nt = wave; nt < 7; nt += 4) {
            f4 acc0 = {0.f,0.f,0.f,0.f}, acc1 = {0.f,0.f,0.f,0.f};
            gemm_nt(a, wB, nt * 16, acc0, acc1);
            int o = nt * 16 + frow;
#pragma unroll
            for (int r = 0; r < 4; ++r) {
                sB[pxb + r][o]      = f2bf(acc0[r]);
                sB[16 + pxb + r][o] = f2bf(acc1[r]);
            }
        }
    }
    __syncthreads();

    // ---------------- bc[px][k] = dot(Bv, Cv) -----------------------------------
    if (tid < TP * NK) {
        int px = tid & 31, k = tid >> 5;
        float a = 0.f;
        for (int s = 0; s < DST; ++s)
            a += bf2f(sB[px][k*28 + DTR + s]) * bf2f(sB[px][k*28 + DTR + DST + s]);
        sbc[px][k] = a;
    }
    __syncthreads();

    // ---------------- dt/gain + y = xss*gain, LN2, *z -> sA ---------------------
    {
        const int px = tid & 31, part = tid >> 5;
        float dtf[NK][DTR];
#pragma unroll
        for (int k = 0; k < NK; ++k)
#pragma unroll
            for (int r = 0; r < DTR; ++r)
                dtf[k][r] = bf2f(sB[px][k*28 + r]);
        float bck[NK] = { sbc[px][0], sbc[px][1], sbc[px][2], sbc[px][3] };

        float sum = 0.f, sq = 0.f;
        for (int i = 0; i < 24; ++i) {
            int c = part * 24 + i;
            float g = 0.f;
#pragma unroll
            for (int k = 0; k < NK; ++k) {
                const float* dw = dt_w + ((size_t)(k * CC + c)) * DTR;
                float4 d0 = *(const float4*)(dw);
                float4 d1 = *(const float4*)(dw + 4);
                float4 d2 = *(const float4*)(dw + 8);
                float dot = dt_b[k * CC + c];
                dot += dtf[k][0]*d0.x + dtf[k][1]*d0.y + dtf[k][2]*d0.z + dtf[k][3]*d0.w;
                dot += dtf[k][4]*d1.x + dtf[k][5]*d1.y + dtf[k][6]*d1.z + dtf[k][7]*d1.w;
                dot += dtf[k][8]*d2.x + dtf[k][9]*d2.y + dtf[k][10]*d2.z + dtf[k][11]*d2.w;
                g += bck[k] * softplusf(dot) + Ds[k * CC + c];
            }
            float yv = bf2f(sA[px][c]) * g;
            sum += yv; sq += yv * yv;
            sA[px][c] = f2bf(yv);
        }
        sred[px][part] = sum; sred2[px][part] = sq;
        __syncthreads();
        if (part == 0) {
            float s = 0.f, q = 0.f;
            for (int j = 0; j < 8; ++j) { s += sred[px][j]; q += sred2[px][j]; }
            float mu  = s * (1.f / CC);
            float var = q * (1.f / CC) - mu * mu;
            smu[px] = mu; srs[px] = rsqrtf(var + 1e-5f);
        }
        __syncthreads();
        const float mu = smu[px], rs = srs[px];
        for (int i = 0; i < 24; ++i) {
            int c = part * 24 + i;
            float v = bf2f(sA[px][c]);
            v = (v - mu) * rs * out_norm_w[c] + out_norm_b[c];
            v *= bf2f(sZ[px][c]);
            sA[px][c] = f2bf(v);
        }
        __syncthreads();
    }

    // ---------------- GEMM4: s = yz @ ssm_out^T; sB = s * silu(x2) --------------
    {
        bh8 a[2][6]; load_a(&sA[0][0], a);
        const unsigned short* wB = wsb + OFF_SSMOUT;
        for (int nt = wave; nt < 12; nt += 4) {
            f4 acc0 = {0.f,0.f,0.f,0.f}, acc1 = {0.f,0.f,0.f,0.f};
            gemm_nt(a, wB, nt * 16, acc0, acc1);
            int o = nt * 16 + frow;
#pragma unroll
            for (int r = 0; r < 4; ++r) {
                sB[pxb + r][o]      = f2bf(acc0[r] * bf2f(sX2[pxb + r][o]));
                sB[16 + pxb + r][o] = f2bf(acc1[r] * bf2f(sX2[16 + pxb + r][o]));
            }
        }
    }
    __syncthreads();

    // ---------------- GEMM5: o = sB @ w_out^T; out = x + o ----------------------
    {
        bh8 a[2][6]; load_a(&sB[0][0], a);
        const unsigned short* wB = wsb + OFF_WOUT;
        for (int nt = wave; nt < 12; nt += 4) {
            f4 acc0 = {0.f,0.f,0.f,0.f}, acc1 = {0.f,0.f,0.f,0.f};
            gemm_nt(a, wB, nt * 16, acc0, acc1);
            int o = nt * 16 + frow;
            const size_t g0 = (((size_t)b * CC + o) * HH + h) * WW + w0g;
#pragma unroll
            for (int r = 0; r < 4; ++r) {
                out[g0 + pxb + r]      = x[g0 + pxb + r]      + acc0[r];
                out[g0 + 16 + pxb + r] = x[g0 + 16 + pxb + r] + acc1[r];
            }
        }
    }
}

extern "C" void kernel_launch(void* const* d_in, const int* in_sizes, int n_in,
                              void* d_out, int out_size, void* d_ws, size_t ws_size,
                              hipStream_t stream) {
    const float* x          = (const float*)d_in[0];
    const float* norm_w     = (const float*)d_in[1];
    const float* norm_b     = (const float*)d_in[2];
    const float* w_in       = (const float*)d_in[3];
    const float* ssm_in_w   = (const float*)d_in[4];
    const float* x_proj_w   = (const float*)d_in[5];
    const float* dt_w       = (const float*)d_in[6];
    const float* dt_b       = (const float*)d_in[7];
    // d_in[8] = A_logs : unused by the reference computation
    const float* Ds         = (const float*)d_in[9];
    const float* out_norm_w = (const float*)d_in[10];
    const float* out_norm_b = (const float*)d_in[11];
    const float* ssm_out_w  = (const float*)d_in[12];
    const float* w_out      = (const float*)d_in[13];

    unsigned short* wb = (unsigned short*)d_ws;
    prep_w<<<dim3((WTOT + NTH - 1) / NTH), dim3(NTH), 0, stream>>>(
        w_in, ssm_in_w, x_proj_w, ssm_out_w, w_out, wb);

    mamba_fused<<<dim3(2048), dim3(NTH), 0, stream>>>(
        x, norm_w, norm_b, dt_w, dt_b, Ds, out_norm_w, out_norm_b,
        wb, (float*)d_out);
}

// Round 3
// 176.347 us; speedup vs baseline: 19.3229x; 1.7133x over previous
//
#include <hip/hip_runtime.h>
#include <hip/hip_bf16.h>
#include <math.h>

// ChannelMambaBlock fused — Round 3: MFMA dt-einsum + native-exp2 transcendentals
// B=4, C=192, H=128, W=128, K=4, DSTATE=8, DTRANK=12
// One WG = 32 consecutive-W pixels, 256 threads = 4 waves.
// All five K=192 GEMMs + the dt einsum (K=12 padded to 32, dt_b folded in as
// A-col 31 == 1.0) run on v_mfma_f32_16x16x32_bf16. softplus/silu use native
// v_exp_f32/v_log_f32/v_rcp_f32 (args <= 0 -> no overflow).

#define CC    192
#define HH    128
#define WW    128
#define NK    4
#define DST   8
#define DTR   12
#define TP    32
#define SP    200         // LDS row stride for sA/sB (400B rows, 16B-aligned)
#define NTH   256

typedef __attribute__((ext_vector_type(8))) short bh8;   // 8 bf16 = 4 VGPR
typedef __attribute__((ext_vector_type(4))) float f4;

// bf16 weight segments inside d_ws (ushort elems)
#define OFF_WIN    0
#define OFF_SSMIN  73728        // 384*192
#define OFF_XPROJ  147456
#define OFF_SSMOUT 168960       // + 112*192
#define OFF_WOUT   205824
#define OFF_DTW    242688       // + 192*192  -> B_dt [k][c][32]
#define WTOT2      267264       // + 4*192*32
// f32 Dsum[192] lives at byte offset WTOT2*2 (16B aligned)

__device__ __forceinline__ float bf2f(unsigned short u) {
    union { unsigned int i; float f; } v; v.i = ((unsigned int)u) << 16; return v.f;
}
__device__ __forceinline__ unsigned short f2bf(float f) {
    union { float f; unsigned int i; } v; v.f = f;
    unsigned int r = (v.i + 0x7fffu + ((v.i >> 16) & 1u)) >> 16;  // RNE
    return (unsigned short)r;
}
#define LOG2E 1.44269504f
#define LN2   0.69314718f
__device__ __forceinline__ float silu_fast(float x) {
    float e = __builtin_amdgcn_exp2f(-LOG2E * x);          // 2^(-x*log2e) = e^-x
    return x * __builtin_amdgcn_rcpf(1.f + e);
}
__device__ __forceinline__ float softplus_fast(float x) {
    float e = __builtin_amdgcn_exp2f(-LOG2E * fabsf(x));   // e^-|x| <= 1
    return fmaxf(x, 0.f) + LN2 * __builtin_amdgcn_logf(1.f + e);
}

extern "C" __global__ void prep_w(const float* __restrict__ w_in,
                                  const float* __restrict__ ssm_in_w,
                                  const float* __restrict__ x_proj_w,
                                  const float* __restrict__ ssm_out_w,
                                  const float* __restrict__ w_out,
                                  const float* __restrict__ dt_w,
                                  const float* __restrict__ dt_b,
                                  const float* __restrict__ Ds,
                                  unsigned short* __restrict__ wb)
{
    int i = blockIdx.x * NTH + threadIdx.x;
    if (i < OFF_DTW) {
        float v;
        if      (i < OFF_XPROJ ) v = (i < OFF_SSMIN) ? w_in[i] : ssm_in_w[i - OFF_SSMIN];
        else if (i < OFF_SSMOUT) v = x_proj_w[i - OFF_XPROJ];
        else if (i < OFF_WOUT  ) v = ssm_out_w[i - OFF_SSMOUT];
        else                     v = w_out[i - OFF_WOUT];
        wb[i] = f2bf(v);
    } else if (i < WTOT2) {
        int j  = i - OFF_DTW;
        int r  = j & 31;
        int kc = j >> 5;                       // k*192 + c
        float v = (r < DTR) ? dt_w[kc * DTR + r]
                            : (r == 31 ? dt_b[kc] : 0.f);
        wb[i] = f2bf(v);
    } else if (i < WTOT2 + CC) {
        int c = i - WTOT2;
        float* dsum = (float*)(wb + WTOT2);
        dsum[c] = Ds[c] + Ds[CC + c] + Ds[2*CC + c] + Ds[3*CC + c];
    }
}

extern "C" __global__ void __launch_bounds__(NTH, 3)
mamba_fused(const float* __restrict__ x,
            const float* __restrict__ norm_w,  const float* __restrict__ norm_b,
            const float* __restrict__ out_norm_w, const float* __restrict__ out_norm_b,
            const unsigned short* __restrict__ wsb,
            float* __restrict__ out)
{
    __shared__ __align__(16) unsigned short sA [TP][SP];
    __shared__ __align__(16) unsigned short sB [TP][SP];
    __shared__ __align__(16) unsigned short sZ [TP][CC];
    __shared__ __align__(16) unsigned short sX2[TP][CC];
    __shared__ float sred [TP][8];
    __shared__ float sred2[TP][8];
    __shared__ float smu[TP];
    __shared__ float srs[TP];
    __shared__ __align__(16) float sbcT[NK][TP];

    const int tid  = threadIdx.x;
    const int lane = tid & 63;
    const int wave = tid >> 6;
    const int frow = lane & 15;
    const int kb   = lane >> 4;
    const int pxb  = kb * 4;

    const int t   = blockIdx.x;
    const int b   = t >> 9;
    const int rem = t & 511;
    const int h   = rem >> 2;
    const int w0g = (rem & 3) * TP;

    const float* dsum = (const float*)(wsb + WTOT2);

    // ---------------- Phase 0: load x + LayerNorm1 -> sA = xn (bf16) -------------
    {
        const int px = tid & 31, part = tid >> 5;
        float sum = 0.f, sq = 0.f;
        const size_t base = (((size_t)b * CC) * HH + h) * WW + w0g + px;
        for (int i = 0; i < 24; ++i) {
            int c = part * 24 + i;
            float v = x[base + (size_t)c * (HH * WW)];
            sum += v; sq += v * v;
            sA[px][c] = f2bf(v);
        }
        sred[px][part] = sum; sred2[px][part] = sq;
        __syncthreads();
        if (part == 0) {
            float s = 0.f, q = 0.f;
            for (int j = 0; j < 8; ++j) { s += sred[px][j]; q += sred2[px][j]; }
            float mu  = s * (1.f / CC);
            float var = q * (1.f / CC) - mu * mu;
            smu[px] = mu; srs[px] = rsqrtf(var + 1e-5f);
        }
        __syncthreads();
        const float mu = smu[px], rs = srs[px];
        for (int i = 0; i < 24; ++i) {
            int c = part * 24 + i;
            float v = bf2f(sA[px][c]);
            v = (v - mu) * rs * norm_w[c] + norm_b[c];
            sA[px][c] = f2bf(v);
        }
        __syncthreads();
    }

    auto load_a = [&](const unsigned short* sSrc, bh8 a[2][6]) {
#pragma unroll
        for (int m = 0; m < 2; ++m)
#pragma unroll
            for (int ks = 0; ks < 6; ++ks)
                a[m][ks] = *(const bh8*)(sSrc + (m * 16 + frow) * SP + ks * 32 + kb * 8);
    };
    auto gemm_nt = [&](const bh8 a[2][6], const unsigned short* wB, int n0,
                       f4& acc0, f4& acc1) {
        const unsigned short* wp = wB + (size_t)(n0 + frow) * CC + kb * 8;
#pragma unroll
        for (int ks = 0; ks < 6; ++ks) {
            bh8 bf = *(const bh8*)(wp + ks * 32);
            acc0 = __builtin_amdgcn_mfma_f32_16x16x32_bf16(a[0][ks], bf, acc0, 0, 0, 0);
            acc1 = __builtin_amdgcn_mfma_f32_16x16x32_bf16(a[1][ks], bf, acc1, 0, 0, 0);
        }
    };

    // ---------------- GEMM1: p = xn @ w_in^T -> sB=x1, sX2=silu(x2) --------------
    {
        bh8 a[2][6]; load_a(&sA[0][0], a);
        const unsigned short* wB = wsb + OFF_WIN;
        for (int nt = wave; nt < 24; nt += 4) {
            f4 acc0 = {0.f,0.f,0.f,0.f}, acc1 = {0.f,0.f,0.f,0.f};
            gemm_nt(a, wB, nt * 16, acc0, acc1);
            int o = nt * 16 + frow;
            if (o < CC) {
#pragma unroll
                for (int r = 0; r < 4; ++r) {
                    sB[pxb + r][o]      = f2bf(acc0[r]);
                    sB[16 + pxb + r][o] = f2bf(acc1[r]);
                }
            } else {
                int oc = o - CC;
#pragma unroll
                for (int r = 0; r < 4; ++r) {
                    sX2[pxb + r][oc]      = f2bf(silu_fast(acc0[r]));
                    sX2[16 + pxb + r][oc] = f2bf(silu_fast(acc1[r]));
                }
            }
        }
    }
    __syncthreads();

    // ---------------- GEMM2: u = x1 @ ssm_in^T -> sA=silu(xss), sZ=silu(z) -------
    {
        bh8 a[2][6]; load_a(&sB[0][0], a);
        const unsigned short* wB = wsb + OFF_SSMIN;
        for (int nt = wave; nt < 24; nt += 4) {
            f4 acc0 = {0.f,0.f,0.f,0.f}, acc1 = {0.f,0.f,0.f,0.f};
            gemm_nt(a, wB, nt * 16, acc0, acc1);
            int o = nt * 16 + frow;
            if (o < CC) {
#pragma unroll
                for (int r = 0; r < 4; ++r) {
                    sA[pxb + r][o]      = f2bf(silu_fast(acc0[r]));
                    sA[16 + pxb + r][o] = f2bf(silu_fast(acc1[r]));
                }
            } else {
                int oc = o - CC;
#pragma unroll
                for (int r = 0; r < 4; ++r) {
                    sZ[pxb + r][oc]      = f2bf(silu_fast(acc0[r]));
                    sZ[16 + pxb + r][oc] = f2bf(silu_fast(acc1[r]));
                }
            }
        }
    }
    __syncthreads();

    // ---------------- GEMM3: xd = xss @ x_proj^T (N=112) -> sB ------------------
    {
        bh8 a[2][6]; load_a(&sA[0][0], a);
        const unsigned short* wB = wsb + OFF_XPROJ;
        for (int nt = wave; nt < 7; nt += 4) {
            f4 acc0 = {0.f,0.f,0.f,0.f}, acc1 = {0.f,0.f,0.f,0.f};
            gemm_nt(a, wB, nt * 16, acc0, acc1);
            int o = nt * 16 + frow;
#pragma unroll
            for (int r = 0; r < 4; ++r) {
                sB[pxb + r][o]      = f2bf(acc0[r]);
                sB[16 + pxb + r][o] = f2bf(acc1[r]);
            }
        }
    }
    __syncthreads();

    // ---------------- bc[k][px] = dot(Bv, Cv) (transposed for vector reads) -----
    if (tid < TP * NK) {
        int px = tid & 31, k = tid >> 5;
        float a = 0.f;
        for (int s = 0; s < DST; ++s)
            a += bf2f(sB[px][k*28 + DTR + s]) * bf2f(sB[px][k*28 + DTR + DST + s]);
        sbcT[k][px] = a;
    }
    __syncthreads();

    // ---------------- dt-MFMA: gain = sum_k bc*softplus(dtr@dt_w + dt_b) --------
    // A (per k): cols 0..11 = dtr (from sB), col 31 = 1.0 (dt_b), rest 0.
    {
        bh8 adt[NK][2];
#pragma unroll
        for (int k = 0; k < NK; ++k)
#pragma unroll
            for (int m = 0; m < 2; ++m) {
                const unsigned short* rp = &sB[m * 16 + frow][k * 28];
                bh8 v;
                if (kb == 0) {
                    ushort4 lo = *(const ushort4*)(rp);
                    ushort4 hi = *(const ushort4*)(rp + 4);
                    v = bh8{(short)lo.x,(short)lo.y,(short)lo.z,(short)lo.w,
                            (short)hi.x,(short)hi.y,(short)hi.z,(short)hi.w};
                } else if (kb == 1) {
                    ushort4 lo = *(const ushort4*)(rp + 8);
                    v = bh8{(short)lo.x,(short)lo.y,(short)lo.z,(short)lo.w,0,0,0,0};
                } else if (kb == 2) {
                    v = bh8{0,0,0,0,0,0,0,0};
                } else {
                    v = bh8{0,0,0,0,0,0,0,(short)0x3F80};   // bf16 1.0 at col 31
                }
                adt[k][m] = v;
            }
        f4 bc0[NK], bc1[NK];
#pragma unroll
        for (int k = 0; k < NK; ++k) {
            bc0[k] = *(const f4*)(&sbcT[k][pxb]);
            bc1[k] = *(const f4*)(&sbcT[k][16 + pxb]);
        }
        const unsigned short* wDT = wsb + OFF_DTW;
        for (int ct = wave; ct < 12; ct += 4) {
            int c = ct * 16 + frow;
            f4 g0 = {0.f,0.f,0.f,0.f}, g1 = {0.f,0.f,0.f,0.f};
#pragma unroll
            for (int k = 0; k < NK; ++k) {
                bh8 bf = *(const bh8*)(wDT + (((size_t)(k * CC + c)) << 5) + kb * 8);
                f4 d0 = {0.f,0.f,0.f,0.f}, d1 = {0.f,0.f,0.f,0.f};
                d0 = __builtin_amdgcn_mfma_f32_16x16x32_bf16(adt[k][0], bf, d0, 0, 0, 0);
                d1 = __builtin_amdgcn_mfma_f32_16x16x32_bf16(adt[k][1], bf, d1, 0, 0, 0);
#pragma unroll
                for (int r = 0; r < 4; ++r) {
                    g0[r] += bc0[k][r] * softplus_fast(d0[r]);
                    g1[r] += bc1[k][r] * softplus_fast(d1[r]);
                }
            }
            float ds = dsum[c];
#pragma unroll
            for (int r = 0; r < 4; ++r) {
                float y0 = bf2f(sA[pxb + r][c]) * (g0[r] + ds);
                sA[pxb + r][c] = f2bf(y0);
                float y1 = bf2f(sA[16 + pxb + r][c]) * (g1[r] + ds);
                sA[16 + pxb + r][c] = f2bf(y1);
            }
        }
    }
    __syncthreads();

    // ---------------- LN2 over y, then *silu(z) -> sA ---------------------------
    {
        const int px = tid & 31, part = tid >> 5;
        float sum = 0.f, sq = 0.f;
        for (int i = 0; i < 24; ++i) {
            int c = part * 24 + i;
            float v = bf2f(sA[px][c]);
            sum += v; sq += v * v;
        }
        sred[px][part] = sum; sred2[px][part] = sq;
        __syncthreads();
        if (part == 0) {
            float s = 0.f, q = 0.f;
            for (int j = 0; j < 8; ++j) { s += sred[px][j]; q += sred2[px][j]; }
            float mu  = s * (1.f / CC);
            float var = q * (1.f / CC) - mu * mu;
            smu[px] = mu; srs[px] = rsqrtf(var + 1e-5f);
        }
        __syncthreads();
        const float mu = smu[px], rs = srs[px];
        for (int i = 0; i < 24; ++i) {
            int c = part * 24 + i;
            float v = bf2f(sA[px][c]);
            v = (v - mu) * rs * out_norm_w[c] + out_norm_b[c];
            v *= bf2f(sZ[px][c]);
            sA[px][c] = f2bf(v);
        }
        __syncthreads();
    }

    // ---------------- GEMM4: s = yz @ ssm_out^T; sB = s * silu(x2) --------------
    {
        bh8 a[2][6]; load_a(&sA[0][0], a);
        const unsigned short* wB = wsb + OFF_SSMOUT;
        for (int nt = wave; nt < 12; nt += 4) {
            f4 acc0 = {0.f,0.f,0.f,0.f}, acc1 = {0.f,0.f,0.f,0.f};
            gemm_nt(a, wB, nt * 16, acc0, acc1);
            int o = nt * 16 + frow;
#pragma unroll
            for (int r = 0; r < 4; ++r) {
                sB[pxb + r][o]      = f2bf(acc0[r] * bf2f(sX2[pxb + r][o]));
                sB[16 + pxb + r][o] = f2bf(acc1[r] * bf2f(sX2[16 + pxb + r][o]));
            }
        }
    }
    __syncthreads();

    // ---------------- GEMM5: o = sB @ w_out^T; out = x + o ----------------------
    {
        bh8 a[2][6]; load_a(&sB[0][0], a);
        const unsigned short* wB = wsb + OFF_WOUT;
        for (int nt = wave; nt < 12; nt += 4) {
            f4 acc0 = {0.f,0.f,0.f,0.f}, acc1 = {0.f,0.f,0.f,0.f};
            gemm_nt(a, wB, nt * 16, acc0, acc1);
            int o = nt * 16 + frow;
            const size_t g0 = (((size_t)b * CC + o) * HH + h) * WW + w0g;
#pragma unroll
            for (int r = 0; r < 4; ++r) {
                out[g0 + pxb + r]      = x[g0 + pxb + r]      + acc0[r];
                out[g0 + 16 + pxb + r] = x[g0 + 16 + pxb + r] + acc1[r];
            }
        }
    }
}

extern "C" void kernel_launch(void* const* d_in, const int* in_sizes, int n_in,
                              void* d_out, int out_size, void* d_ws, size_t ws_size,
                              hipStream_t stream) {
    const float* x          = (const float*)d_in[0];
    const float* norm_w     = (const float*)d_in[1];
    const float* norm_b     = (const float*)d_in[2];
    const float* w_in       = (const float*)d_in[3];
    const float* ssm_in_w   = (const float*)d_in[4];
    const float* x_proj_w   = (const float*)d_in[5];
    const float* dt_w       = (const float*)d_in[6];
    const float* dt_b       = (const float*)d_in[7];
    // d_in[8] = A_logs : unused by the reference computation
    const float* Ds         = (const float*)d_in[9];
    const float* out_norm_w = (const float*)d_in[10];
    const float* out_norm_b = (const float*)d_in[11];
    const float* ssm_out_w  = (const float*)d_in[12];
    const float* w_out      = (const float*)d_in[13];

    unsigned short* wb = (unsigned short*)d_ws;
    int prep_n = WTOT2 + CC;
    prep_w<<<dim3((prep_n + NTH - 1) / NTH), dim3(NTH), 0, stream>>>(
        w_in, ssm_in_w, x_proj_w, ssm_out_w, w_out, dt_w, dt_b, Ds, wb);

    mamba_fused<<<dim3(2048), dim3(NTH), 0, stream>>>(
        x, norm_w, norm_b, out_norm_w, out_norm_b, wb, (float*)d_out);
}

// Round 4
// 152.589 us; speedup vs baseline: 22.3316x; 1.1557x over previous
//
#include <hip/hip_runtime.h>
#include <hip/hip_bf16.h>
#include <math.h>

// ChannelMambaBlock fused — Round 4: occupancy 4 blocks/CU + 2x MFMA ILP
// B=4, C=192, H=128, W=128, K=4, DSTATE=8, DTRANK=12
// One WG = 32 consecutive-W pixels, 256 threads = 4 waves.
// vs R3: sX2 eliminated (silu(x2) packed bf16 in registers; producer GEMM1 tile
// nt=12+w+4j and consumer GEMM4 tile nt=w+4j share the exact lane mapping),
// LDS 53->39.75KB (4 blocks/CU), GEMM inner loops process n-tile PAIRS
// (4 independent MFMA chains/wave), f2bf via compiler cast.

#define CC    192
#define HH    128
#define WW    128
#define NK    4
#define DST   8
#define DTR   12
#define TP    32
#define SP    200         // LDS row stride (400B rows: 16B-aligned, conflict-free)
#define NTH   256

typedef __attribute__((ext_vector_type(8))) short bh8;   // 8 bf16 = 4 VGPR
typedef __attribute__((ext_vector_type(4))) float f4;

// bf16 weight segments inside d_ws (ushort elems)
#define OFF_WIN    0
#define OFF_SSMIN  73728        // 384*192
#define OFF_XPROJ  147456
#define OFF_SSMOUT 168960       // + 112*192
#define OFF_WOUT   205824
#define OFF_DTW    242688       // + 192*192  -> B_dt [k][c][32]
#define WTOT2      267264       // + 4*192*32
// f32 Dsum[192] at ushort offset WTOT2

#define MFMA(va, vb, vc) __builtin_amdgcn_mfma_f32_16x16x32_bf16(va, vb, vc, 0, 0, 0)

__device__ __forceinline__ float bf2f(unsigned short u) {
    union { unsigned int i; float f; } v; v.i = ((unsigned int)u) << 16; return v.f;
}
__device__ __forceinline__ unsigned short f2bf(float f) {
    __hip_bfloat16 h = __float2bfloat16(f);
    unsigned short u; __builtin_memcpy(&u, &h, 2); return u;
}
__device__ __forceinline__ unsigned int pk2(float a, float b) {
    return (unsigned int)f2bf(a) | ((unsigned int)f2bf(b) << 16);
}
__device__ __forceinline__ float lo16(unsigned int u) { return bf2f((unsigned short)(u & 0xffffu)); }
__device__ __forceinline__ float hi16(unsigned int u) { return bf2f((unsigned short)(u >> 16)); }

#define LOG2E 1.44269504f
#define LN2   0.69314718f
__device__ __forceinline__ float silu_fast(float x) {
    float e = __builtin_amdgcn_exp2f(-LOG2E * x);
    return x * __builtin_amdgcn_rcpf(1.f + e);
}
__device__ __forceinline__ float softplus_fast(float x) {
    float e = __builtin_amdgcn_exp2f(-LOG2E * fabsf(x));
    return fmaxf(x, 0.f) + LN2 * __builtin_amdgcn_logf(1.f + e);
}

extern "C" __global__ void prep_w(const float* __restrict__ w_in,
                                  const float* __restrict__ ssm_in_w,
                                  const float* __restrict__ x_proj_w,
                                  const float* __restrict__ ssm_out_w,
                                  const float* __restrict__ w_out,
                                  const float* __restrict__ dt_w,
                                  const float* __restrict__ dt_b,
                                  const float* __restrict__ Ds,
                                  unsigned short* __restrict__ wb)
{
    int i = blockIdx.x * NTH + threadIdx.x;
    if (i < OFF_DTW) {
        float v;
        if      (i < OFF_XPROJ ) v = (i < OFF_SSMIN) ? w_in[i] : ssm_in_w[i - OFF_SSMIN];
        else if (i < OFF_SSMOUT) v = x_proj_w[i - OFF_XPROJ];
        else if (i < OFF_WOUT  ) v = ssm_out_w[i - OFF_SSMOUT];
        else                     v = w_out[i - OFF_WOUT];
        wb[i] = f2bf(v);
    } else if (i < WTOT2) {
        int j  = i - OFF_DTW;
        int r  = j & 31;
        int kc = j >> 5;
        float v = (r < DTR) ? dt_w[kc * DTR + r]
                            : (r == 31 ? dt_b[kc] : 0.f);
        wb[i] = f2bf(v);
    } else if (i < WTOT2 + CC) {
        int c = i - WTOT2;
        float* dsum = (float*)(wb + WTOT2);
        dsum[c] = Ds[c] + Ds[CC + c] + Ds[2*CC + c] + Ds[3*CC + c];
    }
}

extern "C" __global__ void __launch_bounds__(NTH, 4)
mamba_fused(const float* __restrict__ x,
            const float* __restrict__ norm_w,  const float* __restrict__ norm_b,
            const float* __restrict__ out_norm_w, const float* __restrict__ out_norm_b,
            const unsigned short* __restrict__ wsb,
            float* __restrict__ out)
{
    __shared__ __align__(16) unsigned short sA [TP][SP];   // 12800 B
    __shared__ __align__(16) unsigned short sB [TP][SP];   // 12800 B
    __shared__ __align__(16) unsigned short sZ [TP][CC];   // 12288 B
    __shared__ float sred [TP][8];                          // 1024 B
    __shared__ float sred2[TP][8];                          // 1024 B
    __shared__ float smu[TP];                               // 128 B
    __shared__ float srs[TP];                               // 128 B
    __shared__ __align__(16) float sbcT[NK][TP];            // 512 B   => 40704 B total

    const int tid  = threadIdx.x;
    const int lane = tid & 63;
    const int wave = tid >> 6;
    const int frow = lane & 15;
    const int kb   = lane >> 4;
    const int pxb  = kb * 4;

    const int t   = blockIdx.x;
    const int b   = t >> 9;
    const int rem = t & 511;
    const int h   = rem >> 2;
    const int w0g = (rem & 3) * TP;

    const float* dsum = (const float*)(wsb + WTOT2);

    // silu(x2) register storage: [tile j][m-half], each uint2 = 4 bf16 values
    uint2 x2a0, x2a1, x2a2, x2b0, x2b1, x2b2;

    // ---------------- Phase 0: load x + LayerNorm1 -> sA = xn (bf16) -------------
    {
        const int px = tid & 31, part = tid >> 5;
        float sum = 0.f, sq = 0.f;
        const size_t base = (((size_t)b * CC) * HH + h) * WW + w0g + px;
        for (int i = 0; i < 24; ++i) {
            int c = part * 24 + i;
            float v = x[base + (size_t)c * (HH * WW)];
            sum += v; sq += v * v;
            sA[px][c] = f2bf(v);
        }
        sred[px][part] = sum; sred2[px][part] = sq;
        __syncthreads();
        if (part == 0) {
            float s = 0.f, q = 0.f;
            for (int j = 0; j < 8; ++j) { s += sred[px][j]; q += sred2[px][j]; }
            float mu  = s * (1.f / CC);
            float var = q * (1.f / CC) - mu * mu;
            smu[px] = mu; srs[px] = rsqrtf(var + 1e-5f);
        }
        __syncthreads();
        const float mu = smu[px], rs = srs[px];
        for (int i = 0; i < 24; ++i) {
            int c = part * 24 + i;
            float v = bf2f(sA[px][c]);
            v = (v - mu) * rs * norm_w[c] + norm_b[c];
            sA[px][c] = f2bf(v);
        }
        __syncthreads();
    }

    auto load_a = [&](const unsigned short* sSrc, bh8 a[2][6]) {
#pragma unroll
        for (int m = 0; m < 2; ++m)
#pragma unroll
            for (int ks = 0; ks < 6; ++ks)
                a[m][ks] = *(const bh8*)(sSrc + (m * 16 + frow) * SP + ks * 32 + kb * 8);
    };
    // two n-tiles at once: 4 independent MFMA chains
    auto gemm_pair = [&](const bh8 a[2][6], const unsigned short* wB, int n0, int n1,
                         f4& p0, f4& p1, f4& q0, f4& q1) {
        const unsigned short* wp0 = wB + (size_t)(n0 + frow) * CC + kb * 8;
        const unsigned short* wp1 = wB + (size_t)(n1 + frow) * CC + kb * 8;
#pragma unroll
        for (int ks = 0; ks < 6; ++ks) {
            bh8 b0 = *(const bh8*)(wp0 + ks * 32);
            bh8 b1 = *(const bh8*)(wp1 + ks * 32);
            p0 = MFMA(a[0][ks], b0, p0);
            p1 = MFMA(a[1][ks], b0, p1);
            q0 = MFMA(a[0][ks], b1, q0);
            q1 = MFMA(a[1][ks], b1, q1);
        }
    };
    auto gemm_one = [&](const bh8 a[2][6], const unsigned short* wB, int n0,
                        f4& p0, f4& p1) {
        const unsigned short* wp = wB + (size_t)(n0 + frow) * CC + kb * 8;
#pragma unroll
        for (int ks = 0; ks < 6; ++ks) {
            bh8 bf = *(const bh8*)(wp + ks * 32);
            p0 = MFMA(a[0][ks], bf, p0);
            p1 = MFMA(a[1][ks], bf, p1);
        }
    };
    // epilogue helpers
    auto st_sB = [&](int o, const f4& c0, const f4& c1) {
#pragma unroll
        for (int r = 0; r < 4; ++r) {
            sB[pxb + r][o]      = f2bf(c0[r]);
            sB[16 + pxb + r][o] = f2bf(c1[r]);
        }
    };
    auto st_sA_silu = [&](int o, const f4& c0, const f4& c1) {
#pragma unroll
        for (int r = 0; r < 4; ++r) {
            sA[pxb + r][o]      = f2bf(silu_fast(c0[r]));
            sA[16 + pxb + r][o] = f2bf(silu_fast(c1[r]));
        }
    };
    auto st_sZ_silu = [&](int oc, const f4& c0, const f4& c1) {
#pragma unroll
        for (int r = 0; r < 4; ++r) {
            sZ[pxb + r][oc]      = f2bf(silu_fast(c0[r]));
            sZ[16 + pxb + r][oc] = f2bf(silu_fast(c1[r]));
        }
    };
    auto pack_silu = [&](const f4& c) {
        return make_uint2(pk2(silu_fast(c[0]), silu_fast(c[1])),
                          pk2(silu_fast(c[2]), silu_fast(c[3])));
    };

    // ---------------- GEMM1: p = xn @ w_in^T -> sB = x1, regs = silu(x2) --------
    {
        bh8 a[2][6]; load_a(&sA[0][0], a);
        const unsigned short* wB = wsb + OFF_WIN;
        {   // pair 0: tiles (w, w+4) -> both x1
            f4 p0={0,0,0,0},p1={0,0,0,0},q0={0,0,0,0},q1={0,0,0,0};
            gemm_pair(a, wB, wave * 16, (wave + 4) * 16, p0, p1, q0, q1);
            st_sB(wave * 16 + frow, p0, p1);
            st_sB((wave + 4) * 16 + frow, q0, q1);
        }
        {   // pair 1: tile w+8 -> x1, tile w+12 -> x2 slot 0
            f4 p0={0,0,0,0},p1={0,0,0,0},q0={0,0,0,0},q1={0,0,0,0};
            gemm_pair(a, wB, (wave + 8) * 16, (wave + 12) * 16, p0, p1, q0, q1);
            st_sB((wave + 8) * 16 + frow, p0, p1);
            x2a0 = pack_silu(q0); x2b0 = pack_silu(q1);
        }
        {   // pair 2: tiles w+16, w+20 -> x2 slots 1, 2
            f4 p0={0,0,0,0},p1={0,0,0,0},q0={0,0,0,0},q1={0,0,0,0};
            gemm_pair(a, wB, (wave + 16) * 16, (wave + 20) * 16, p0, p1, q0, q1);
            x2a1 = pack_silu(p0); x2b1 = pack_silu(p1);
            x2a2 = pack_silu(q0); x2b2 = pack_silu(q1);
        }
    }
    __syncthreads();

    // ---------------- GEMM2: u = x1 @ ssm_in^T -> sA = silu(xss), sZ = silu(z) --
    {
        bh8 a[2][6]; load_a(&sB[0][0], a);
        const unsigned short* wB = wsb + OFF_SSMIN;
        {   // pair 0: both xss
            f4 p0={0,0,0,0},p1={0,0,0,0},q0={0,0,0,0},q1={0,0,0,0};
            gemm_pair(a, wB, wave * 16, (wave + 4) * 16, p0, p1, q0, q1);
            st_sA_silu(wave * 16 + frow, p0, p1);
            st_sA_silu((wave + 4) * 16 + frow, q0, q1);
        }
        {   // pair 1: w+8 -> xss, w+12 -> z
            f4 p0={0,0,0,0},p1={0,0,0,0},q0={0,0,0,0},q1={0,0,0,0};
            gemm_pair(a, wB, (wave + 8) * 16, (wave + 12) * 16, p0, p1, q0, q1);
            st_sA_silu((wave + 8) * 16 + frow, p0, p1);
            st_sZ_silu((wave + 12) * 16 + frow - CC, q0, q1);
        }
        {   // pair 2: both z
            f4 p0={0,0,0,0},p1={0,0,0,0},q0={0,0,0,0},q1={0,0,0,0};
            gemm_pair(a, wB, (wave + 16) * 16, (wave + 20) * 16, p0, p1, q0, q1);
            st_sZ_silu((wave + 16) * 16 + frow - CC, p0, p1);
            st_sZ_silu((wave + 20) * 16 + frow - CC, q0, q1);
        }
    }
    __syncthreads();

    // ---------------- GEMM3: xd = xss @ x_proj^T (7 tiles; tile 7 = dead junk) --
    {
        bh8 a[2][6]; load_a(&sA[0][0], a);
        const unsigned short* wB = wsb + OFF_XPROJ;
        f4 p0={0,0,0,0},p1={0,0,0,0},q0={0,0,0,0},q1={0,0,0,0};
        gemm_pair(a, wB, wave * 16, (wave + 4) * 16, p0, p1, q0, q1);
        st_sB(wave * 16 + frow, p0, p1);
        st_sB((wave + 4) * 16 + frow, q0, q1);   // wave 3 writes cols 112..127: dead
    }
    __syncthreads();

    // ---------------- bc[k][px] = dot(Bv, Cv) -----------------------------------
    if (tid < TP * NK) {
        int px = tid & 31, k = tid >> 5;
        float a = 0.f;
        for (int s = 0; s < DST; ++s)
            a += bf2f(sB[px][k*28 + DTR + s]) * bf2f(sB[px][k*28 + DTR + DST + s]);
        sbcT[k][px] = a;
    }
    __syncthreads();

    // ---------------- dt-MFMA: gain = sum_k bc*softplus(dtr@dt_w + dt_b) --------
    {
        bh8 adt[NK][2];
#pragma unroll
        for (int k = 0; k < NK; ++k)
#pragma unroll
            for (int m = 0; m < 2; ++m) {
                const unsigned short* rp = &sB[m * 16 + frow][k * 28];
                bh8 v;
                if (kb == 0) {
                    ushort4 lo = *(const ushort4*)(rp);
                    ushort4 hi = *(const ushort4*)(rp + 4);
                    v = bh8{(short)lo.x,(short)lo.y,(short)lo.z,(short)lo.w,
                            (short)hi.x,(short)hi.y,(short)hi.z,(short)hi.w};
                } else if (kb == 1) {
                    ushort4 lo = *(const ushort4*)(rp + 8);
                    v = bh8{(short)lo.x,(short)lo.y,(short)lo.z,(short)lo.w,0,0,0,0};
                } else if (kb == 2) {
                    v = bh8{0,0,0,0,0,0,0,0};
                } else {
                    v = bh8{0,0,0,0,0,0,0,(short)0x3F80};   // bf16 1.0 -> col 31 (dt_b)
                }
                adt[k][m] = v;
            }
        const unsigned short* wDT = wsb + OFF_DTW;
        for (int ct = wave; ct < 12; ct += 4) {
            int c = ct * 16 + frow;
            f4 g0 = {0.f,0.f,0.f,0.f}, g1 = {0.f,0.f,0.f,0.f};
#pragma unroll
            for (int k = 0; k < NK; ++k) {
                bh8 bf = *(const bh8*)(wDT + (((size_t)(k * CC + c)) << 5) + kb * 8);
                f4 d0 = {0.f,0.f,0.f,0.f}, d1 = {0.f,0.f,0.f,0.f};
                d0 = MFMA(adt[k][0], bf, d0);
                d1 = MFMA(adt[k][1], bf, d1);
                f4 bc0 = *(const f4*)(&sbcT[k][pxb]);
                f4 bc1 = *(const f4*)(&sbcT[k][16 + pxb]);
#pragma unroll
                for (int r = 0; r < 4; ++r) {
                    g0[r] += bc0[r] * softplus_fast(d0[r]);
                    g1[r] += bc1[r] * softplus_fast(d1[r]);
                }
            }
            float ds = dsum[c];
#pragma unroll
            for (int r = 0; r < 4; ++r) {
                float y0 = bf2f(sA[pxb + r][c]) * (g0[r] + ds);
                sA[pxb + r][c] = f2bf(y0);
                float y1 = bf2f(sA[16 + pxb + r][c]) * (g1[r] + ds);
                sA[16 + pxb + r][c] = f2bf(y1);
            }
        }
    }
    __syncthreads();

    // ---------------- LN2 over y, then *silu(z) -> sA ---------------------------
    {
        const int px = tid & 31, part = tid >> 5;
        float sum = 0.f, sq = 0.f;
        for (int i = 0; i < 24; ++i) {
            int c = part * 24 + i;
            float v = bf2f(sA[px][c]);
            sum += v; sq += v * v;
        }
        sred[px][part] = sum; sred2[px][part] = sq;
        __syncthreads();
        if (part == 0) {
            float s = 0.f, q = 0.f;
            for (int j = 0; j < 8; ++j) { s += sred[px][j]; q += sred2[px][j]; }
            float mu  = s * (1.f / CC);
            float var = q * (1.f / CC) - mu * mu;
            smu[px] = mu; srs[px] = rsqrtf(var + 1e-5f);
        }
        __syncthreads();
        const float mu = smu[px], rs = srs[px];
        for (int i = 0; i < 24; ++i) {
            int c = part * 24 + i;
            float v = bf2f(sA[px][c]);
            v = (v - mu) * rs * out_norm_w[c] + out_norm_b[c];
            v *= bf2f(sZ[px][c]);
            sA[px][c] = f2bf(v);
        }
        __syncthreads();
    }

    // ---------------- GEMM4: s = yz @ ssm_out^T; sB = s * silu(x2) --------------
    {
        bh8 a[2][6]; load_a(&sA[0][0], a);
        const unsigned short* wB = wsb + OFF_SSMOUT;
        {   // pair: tiles w (x2 slot 0), w+4 (x2 slot 1)
            f4 p0={0,0,0,0},p1={0,0,0,0},q0={0,0,0,0},q1={0,0,0,0};
            gemm_pair(a, wB, wave * 16, (wave + 4) * 16, p0, p1, q0, q1);
            int o0 = wave * 16 + frow, o1 = (wave + 4) * 16 + frow;
            sB[pxb + 0][o0]      = f2bf(p0[0] * lo16(x2a0.x));
            sB[pxb + 1][o0]      = f2bf(p0[1] * hi16(x2a0.x));
            sB[pxb + 2][o0]      = f2bf(p0[2] * lo16(x2a0.y));
            sB[pxb + 3][o0]      = f2bf(p0[3] * hi16(x2a0.y));
            sB[16 + pxb + 0][o0] = f2bf(p1[0] * lo16(x2b0.x));
            sB[16 + pxb + 1][o0] = f2bf(p1[1] * hi16(x2b0.x));
            sB[16 + pxb + 2][o0] = f2bf(p1[2] * lo16(x2b0.y));
            sB[16 + pxb + 3][o0] = f2bf(p1[3] * hi16(x2b0.y));
            sB[pxb + 0][o1]      = f2bf(q0[0] * lo16(x2a1.x));
            sB[pxb + 1][o1]      = f2bf(q0[1] * hi16(x2a1.x));
            sB[pxb + 2][o1]      = f2bf(q0[2] * lo16(x2a1.y));
            sB[pxb + 3][o1]      = f2bf(q0[3] * hi16(x2a1.y));
            sB[16 + pxb + 0][o1] = f2bf(q1[0] * lo16(x2b1.x));
            sB[16 + pxb + 1][o1] = f2bf(q1[1] * hi16(x2b1.x));
            sB[16 + pxb + 2][o1] = f2bf(q1[2] * lo16(x2b1.y));
            sB[16 + pxb + 3][o1] = f2bf(q1[3] * hi16(x2b1.y));
        }
        {   // single: tile w+8 (x2 slot 2)
            f4 p0={0,0,0,0},p1={0,0,0,0};
            gemm_one(a, wB, (wave + 8) * 16, p0, p1);
            int o = (wave + 8) * 16 + frow;
            sB[pxb + 0][o]      = f2bf(p0[0] * lo16(x2a2.x));
            sB[pxb + 1][o]      = f2bf(p0[1] * hi16(x2a2.x));
            sB[pxb + 2][o]      = f2bf(p0[2] * lo16(x2a2.y));
            sB[pxb + 3][o]      = f2bf(p0[3] * hi16(x2a2.y));
            sB[16 + pxb + 0][o] = f2bf(p1[0] * lo16(x2b2.x));
            sB[16 + pxb + 1][o] = f2bf(p1[1] * hi16(x2b2.x));
            sB[16 + pxb + 2][o] = f2bf(p1[2] * lo16(x2b2.y));
            sB[16 + pxb + 3][o] = f2bf(p1[3] * hi16(x2b2.y));
        }
    }
    __syncthreads();

    // ---------------- GEMM5: o = sB @ w_out^T; out = x + o ----------------------
    {
        bh8 a[2][6]; load_a(&sB[0][0], a);
        const unsigned short* wB = wsb + OFF_WOUT;
        auto st_out = [&](int o, const f4& c0, const f4& c1) {
            const size_t g0 = (((size_t)b * CC + o) * HH + h) * WW + w0g;
#pragma unroll
            for (int r = 0; r < 4; ++r) {
                out[g0 + pxb + r]      = x[g0 + pxb + r]      + c0[r];
                out[g0 + 16 + pxb + r] = x[g0 + 16 + pxb + r] + c1[r];
            }
        };
        {   // pair: tiles w, w+4
            f4 p0={0,0,0,0},p1={0,0,0,0},q0={0,0,0,0},q1={0,0,0,0};
            gemm_pair(a, wB, wave * 16, (wave + 4) * 16, p0, p1, q0, q1);
            st_out(wave * 16 + frow, p0, p1);
            st_out((wave + 4) * 16 + frow, q0, q1);
        }
        {   // single: tile w+8
            f4 p0={0,0,0,0},p1={0,0,0,0};
            gemm_one(a, wB, (wave + 8) * 16, p0, p1);
            st_out((wave + 8) * 16 + frow, p0, p1);
        }
    }
}

extern "C" void kernel_launch(void* const* d_in, const int* in_sizes, int n_in,
                              void* d_out, int out_size, void* d_ws, size_t ws_size,
                              hipStream_t stream) {
    const float* x          = (const float*)d_in[0];
    const float* norm_w     = (const float*)d_in[1];
    const float* norm_b     = (const float*)d_in[2];
    const float* w_in       = (const float*)d_in[3];
    const float* ssm_in_w   = (const float*)d_in[4];
    const float* x_proj_w   = (const float*)d_in[5];
    const float* dt_w       = (const float*)d_in[6];
    const float* dt_b       = (const float*)d_in[7];
    // d_in[8] = A_logs : unused by the reference computation
    const float* Ds         = (const float*)d_in[9];
    const float* out_norm_w = (const float*)d_in[10];
    const float* out_norm_b = (const float*)d_in[11];
    const float* ssm_out_w  = (const float*)d_in[12];
    const float* w_out      = (const float*)d_in[13];

    unsigned short* wb = (unsigned short*)d_ws;
    int prep_n = WTOT2 + CC;
    prep_w<<<dim3((prep_n + NTH - 1) / NTH), dim3(NTH), 0, stream>>>(
        w_in, ssm_in_w, x_proj_w, ssm_out_w, w_out, dt_w, dt_b, Ds, wb);

    mamba_fused<<<dim3(2048), dim3(NTH), 0, stream>>>(
        x, norm_w, norm_b, out_norm_w, out_norm_b, wb, (float*)d_out);
}